// Round 7
// baseline (371.652 us; speedup 1.0000x reference)
//
#include <hip/hip_runtime.h>

// ---------------------------------------------------------------------------
// DualGCN round 7: 5 dispatches.
//   1. L0 pair  : A=relu(x Wa0^T+ba0), C=relu(x Wb0^T+bb0)     [x fp32, W fp32->bf16 on the fly]
//   2. S pair 1 : B=spmm_a(A), F=spmm_b(C)                     [in-block rowptr binary search]
//   3. L1 pair  : A=relu(B Wa1^T+ba1), D=relu(F Wb1^T+bb1)
//   4. S pair 2 : Eo=spmm_a(A), B=spmm_b(D)
//   5. LmLo     : x_b=relu([C,D,B] Wm^T+bm); out=[Eo,x_b] Wo^T+bo  (fused)
// bf16 slabs, fp32 accumulation. N=50000, E=800000, H=128, OUT=64.
// ---------------------------------------------------------------------------

typedef short short8 __attribute__((ext_vector_type(8)));
typedef float floatx4 __attribute__((ext_vector_type(4)));
typedef float floatx2 __attribute__((ext_vector_type(2)));
typedef int   intx4   __attribute__((ext_vector_type(4)));
typedef float fltx4   __attribute__((ext_vector_type(4)));
typedef unsigned uintx4 __attribute__((ext_vector_type(4)));

__device__ inline unsigned short f2bf(float f) {
  unsigned u = __builtin_bit_cast(unsigned, f);
  u += 0x7fffu + ((u >> 16) & 1u);      // round-to-nearest-even
  return (unsigned short)(u >> 16);
}
__device__ inline unsigned pack2(float a, float b) {
  return (unsigned)f2bf(a) | ((unsigned)f2bf(b) << 16);
}
__device__ inline float bf_lo(unsigned w) {
  return __builtin_bit_cast(float, w << 16);
}
__device__ inline float bf_hi(unsigned w) {
  return __builtin_bit_cast(float, w & 0xffff0000u);
}
__device__ inline uintx4 pack8(const fltx4& a, const fltx4& b) {
  uintx4 v;
  v.x = pack2(a.x, a.y); v.y = pack2(a.z, a.w);
  v.z = pack2(b.x, b.y); v.w = pack2(b.z, b.w);
  return v;
}

// ---------------------------------------------------------------------------
struct SpmmJob {
  const int* row; const int* col; const float* val;
  const unsigned short* X; unsigned short* Y;
};

// Y[r,:] = sum_e val[e] * X[col[e],:]  (bf16 in, fp32 accum, bf16 out)
// 16 lanes/row, lane owns 8 bf16 (16 B). Edge loop unrolled x8.
// Row boundaries found in-block: 17 threads binary-search the sorted row
// array into LDS (replaces the separate rowptr dispatch).
__global__ __launch_bounds__(256) void spmm_pair_kernel(
    SpmmJob j0, SpmmJob j1, int E, int n)
{
  const SpmmJob J = blockIdx.y ? j1 : j0;
  __shared__ int rp[17];
  const int t = threadIdx.x;
  const int g0 = blockIdx.x * 16;
  if (t < 17) {
    int i = g0 + t; if (i > n) i = n;
    const int* __restrict__ rowp = J.row;
    int lo = 0, hi = E;
    while (lo < hi) {
      int mid = (lo + hi) >> 1;
      if (rowp[mid] < i) lo = mid + 1; else hi = mid;
    }
    rp[t] = lo;
  }
  __syncthreads();

  const int g = g0 + (t >> 4);
  const int lane = t & 15;
  if (g >= n) return;
  const int e0 = rp[t >> 4], e1 = rp[(t >> 4) + 1];
  const size_t loff = (size_t)lane * 8;
  const unsigned short* __restrict__ X = J.X;
  const int* __restrict__ colp = J.col;
  const float* __restrict__ valp = J.val;

  floatx2 ac0 = {0.f, 0.f}, ac1 = {0.f, 0.f};
  floatx2 ac2 = {0.f, 0.f}, ac3 = {0.f, 0.f};

  auto accw = [&](float v, const uintx4& w) {
    floatx2 vv = {v, v};
    floatx2 x0 = {bf_lo(w.x), bf_hi(w.x)};
    floatx2 x1 = {bf_lo(w.y), bf_hi(w.y)};
    floatx2 x2 = {bf_lo(w.z), bf_hi(w.z)};
    floatx2 x3 = {bf_lo(w.w), bf_hi(w.w)};
    ac0 = __builtin_elementwise_fma(vv, x0, ac0);
    ac1 = __builtin_elementwise_fma(vv, x1, ac1);
    ac2 = __builtin_elementwise_fma(vv, x2, ac2);
    ac3 = __builtin_elementwise_fma(vv, x3, ac3);
  };
  auto acc1 = [&](int e) {
    uintx4 w = *(const uintx4*)(X + (size_t)colp[e] * 128 + loff);
    accw(valp[e], w);
  };

  int e = e0;
  int epro = (e0 + 7) & ~7;           // align to 8 for vector col/val loads
  if (epro > e1) epro = e1;
  for (; e < epro; ++e) acc1(e);
  for (; e + 8 <= e1; e += 8) {
    intx4 ca = __builtin_nontemporal_load((const intx4*)(colp + e));
    intx4 cb = __builtin_nontemporal_load((const intx4*)(colp + e + 4));
    fltx4 va = __builtin_nontemporal_load((const fltx4*)(valp + e));
    fltx4 vb = __builtin_nontemporal_load((const fltx4*)(valp + e + 4));
    uintx4 w0 = *(const uintx4*)(X + (size_t)ca.x * 128 + loff);
    uintx4 w1 = *(const uintx4*)(X + (size_t)ca.y * 128 + loff);
    uintx4 w2 = *(const uintx4*)(X + (size_t)ca.z * 128 + loff);
    uintx4 w3 = *(const uintx4*)(X + (size_t)ca.w * 128 + loff);
    uintx4 w4 = *(const uintx4*)(X + (size_t)cb.x * 128 + loff);
    uintx4 w5 = *(const uintx4*)(X + (size_t)cb.y * 128 + loff);
    uintx4 w6 = *(const uintx4*)(X + (size_t)cb.z * 128 + loff);
    uintx4 w7 = *(const uintx4*)(X + (size_t)cb.w * 128 + loff);
    accw(va.x, w0); accw(va.y, w1); accw(va.z, w2); accw(va.w, w3);
    accw(vb.x, w4); accw(vb.y, w5); accw(vb.z, w6); accw(vb.w, w7);
  }
  for (; e < e1; ++e) acc1(e);

  uintx4 o;
  o.x = pack2(ac0[0], ac0[1]); o.y = pack2(ac1[0], ac1[1]);
  o.z = pack2(ac2[0], ac2[1]); o.w = pack2(ac3[0], ac3[1]);
  __builtin_nontemporal_store(o, (uintx4*)(J.Y + (size_t)g * 128 + loff));
}

// ---------------------------------------------------------------------------
struct LinJob {
  const void* X;             // [n,128] bf16 slab (or fp32 if XFP32)
  const float* W;            // [128,128] fp32 row-major
  const float* b;            // [128] fp32
  unsigned short* Y;         // [n,128] bf16
};

// Paired LDS-tiled MFMA GEMM: Y = relu(X @ W.T + b). K=128, HOUT=128, BM=64.
// W staged fp32->bf16 on the fly. 4 waves in 2x2; operand swap (a=W, b=X) so
// each lane's 4 acc regs are 4 consecutive output cols. blockIdx.y = job.
template <bool XFP32>
__global__ __launch_bounds__(256, 3) void mfma_linear_pair_kernel(
    LinJob j0, LinJob j1, int n)
{
  constexpr int LDX = 136;
  __shared__ unsigned short Xs[64 * LDX];   // 17408 B
  __shared__ unsigned short Ws[128 * LDX];  // 34816 B

  const LinJob J = blockIdx.y ? j1 : j0;
  const int tid  = threadIdx.x;
  const int lane = tid & 63;
  const int wave = tid >> 6;
  const int wm   = wave >> 1;     // row half (32 rows)
  const int wn   = wave & 1;      // col half (64 cols)
  const int l15  = lane & 15;
  const int quad = lane >> 4;
  const int row0 = blockIdx.x * 64;

  const int c8   = (tid & 15) * 8;
  const int rloc = tid >> 4;

  // stage X tile: 64 rows x 128 bf16
#pragma unroll
  for (int p = 0; p < 4; ++p) {
    int r = p * 16 + rloc;
    int gr = row0 + r;
    uintx4 v = {0u, 0u, 0u, 0u};
    if (gr < n) {
      if (XFP32) {
        const float* Xr = (const float*)J.X + (size_t)gr * 128 + c8;
        v = pack8(*(const fltx4*)Xr, *(const fltx4*)(Xr + 4));
      } else {
        v = *(const uintx4*)((const unsigned short*)J.X + (size_t)gr * 128 + c8);
      }
    }
    *(uintx4*)(Xs + r * LDX + c8) = v;
  }
  // stage W tile: 128 x 128, fp32 -> bf16
#pragma unroll
  for (int p = 0; p < 8; ++p) {
    int r = p * 16 + rloc;
    const float* Wr = J.W + (size_t)r * 128 + c8;
    *(uintx4*)(Ws + r * LDX + c8) = pack8(*(const fltx4*)Wr, *(const fltx4*)(Wr + 4));
  }
  __syncthreads();

  floatx4 acc[2][4];
#pragma unroll
  for (int i = 0; i < 2; ++i)
#pragma unroll
    for (int j = 0; j < 4; ++j) acc[i][j] = (floatx4){0.f, 0.f, 0.f, 0.f};

#pragma unroll
  for (int k0 = 0; k0 < 128; k0 += 32) {
    const int ko = k0 + quad * 8;
    short8 aW[4], bX[2];
#pragma unroll
    for (int j = 0; j < 4; ++j)
      aW[j] = *(const short8*)(Ws + (wn * 64 + j * 16 + l15) * LDX + ko);
#pragma unroll
    for (int i = 0; i < 2; ++i)
      bX[i] = *(const short8*)(Xs + (wm * 32 + i * 16 + l15) * LDX + ko);
#pragma unroll
    for (int i = 0; i < 2; ++i)
#pragma unroll
      for (int j = 0; j < 4; ++j)
        acc[i][j] = __builtin_amdgcn_mfma_f32_16x16x32_bf16(
            aW[j], bX[i], acc[i][j], 0, 0, 0);
  }

#pragma unroll
  for (int i = 0; i < 2; ++i) {
    int r = row0 + wm * 32 + i * 16 + l15;
    if (r >= n) continue;
#pragma unroll
    for (int j = 0; j < 4; ++j) {
      int c0 = wn * 64 + j * 16 + quad * 4;
      fltx4 bb = *(const fltx4*)(J.b + c0);
      float v0 = fmaxf(acc[i][j][0] + bb.x, 0.f);
      float v1 = fmaxf(acc[i][j][1] + bb.y, 0.f);
      float v2 = fmaxf(acc[i][j][2] + bb.z, 0.f);
      float v3 = fmaxf(acc[i][j][3] + bb.w, 0.f);
      uint2 o; o.x = pack2(v0, v1); o.y = pack2(v2, v3);
      *(uint2*)(J.Y + (size_t)r * 128 + c0) = o;
    }
  }
}

// ---------------------------------------------------------------------------
// Fused merge: x_b = relu([C,D,B] @ Wm.T + bm); out = [Eo, x_b] @ Wo.T + bo.
// Phase 1: K=384 in 3 slab chunks (Wm fp32 staged per chunk), acc -> x_b.
// Phase 2: x_b -> LDS (bf16), Eo tile + full Wo staged, K=256 MFMA, fp32 out.
__global__ __launch_bounds__(256, 2) void lm_lo_fused_kernel(
    const unsigned short* __restrict__ Cs, const unsigned short* __restrict__ Ds,
    const unsigned short* __restrict__ Bs,
    const float* __restrict__ Wm, const float* __restrict__ bm,
    const unsigned short* __restrict__ Eo,
    const float* __restrict__ Wo, const float* __restrict__ bo,
    float* __restrict__ out, int n)
{
  constexpr int LDX = 136;
  __shared__ unsigned short Xs[64 * LDX];   // phase1: X chunk; phase2: x_b
  __shared__ unsigned short U[26112];       // phase1: Ws[128*136]; phase2: Es[64*136] + Wos[64*272]
  unsigned short* Ws  = U;
  unsigned short* Es  = U;
  unsigned short* Wos = U + 64 * LDX;

  const int tid  = threadIdx.x;
  const int lane = tid & 63;
  const int wave = tid >> 6;
  const int wm   = wave >> 1;
  const int wn   = wave & 1;
  const int l15  = lane & 15;
  const int quad = lane >> 4;
  const int row0 = blockIdx.x * 64;

  const int c8   = (tid & 15) * 8;
  const int rloc = tid >> 4;

  // ---- phase 1: x_b accumulation (K=384) ----
  floatx4 acc[2][4];
#pragma unroll
  for (int i = 0; i < 2; ++i)
#pragma unroll
    for (int j = 0; j < 4; ++j) acc[i][j] = (floatx4){0.f, 0.f, 0.f, 0.f};

  for (int kc = 0; kc < 3; ++kc) {
    const unsigned short* Xp = (kc == 0) ? Cs : (kc == 1) ? Ds : Bs;
#pragma unroll
    for (int p = 0; p < 4; ++p) {
      int r = p * 16 + rloc;
      int gr = row0 + r;
      uintx4 v = {0u, 0u, 0u, 0u};
      if (gr < n) v = *(const uintx4*)(Xp + (size_t)gr * 128 + c8);
      *(uintx4*)(Xs + r * LDX + c8) = v;
    }
#pragma unroll
    for (int p = 0; p < 8; ++p) {
      int r = p * 16 + rloc;
      const float* Wr = Wm + (size_t)r * 384 + kc * 128 + c8;
      *(uintx4*)(Ws + r * LDX + c8) = pack8(*(const fltx4*)Wr, *(const fltx4*)(Wr + 4));
    }
    __syncthreads();
#pragma unroll
    for (int k0 = 0; k0 < 128; k0 += 32) {
      const int ko = k0 + quad * 8;
      short8 aW[4], bX[2];
#pragma unroll
      for (int j = 0; j < 4; ++j)
        aW[j] = *(const short8*)(Ws + (wn * 64 + j * 16 + l15) * LDX + ko);
#pragma unroll
      for (int i = 0; i < 2; ++i)
        bX[i] = *(const short8*)(Xs + (wm * 32 + i * 16 + l15) * LDX + ko);
#pragma unroll
      for (int i = 0; i < 2; ++i)
#pragma unroll
        for (int j = 0; j < 4; ++j)
          acc[i][j] = __builtin_amdgcn_mfma_f32_16x16x32_bf16(
              aW[j], bX[i], acc[i][j], 0, 0, 0);
    }
    __syncthreads();
  }

  // ---- phase 2 staging: x_b->Xs, Eo->Es, Wo->Wos ----
  // x_b (relu + bias) into Xs as bf16
#pragma unroll
  for (int i = 0; i < 2; ++i) {
    int r = wm * 32 + i * 16 + l15;
#pragma unroll
    for (int j = 0; j < 4; ++j) {
      int c0 = wn * 64 + j * 16 + quad * 4;
      fltx4 bb = *(const fltx4*)(bm + c0);
      float v0 = fmaxf(acc[i][j][0] + bb.x, 0.f);
      float v1 = fmaxf(acc[i][j][1] + bb.y, 0.f);
      float v2 = fmaxf(acc[i][j][2] + bb.z, 0.f);
      float v3 = fmaxf(acc[i][j][3] + bb.w, 0.f);
      *(unsigned*)(Xs + r * LDX + c0)     = pack2(v0, v1);
      *(unsigned*)(Xs + r * LDX + c0 + 2) = pack2(v2, v3);
    }
  }
  // Eo tile (64 x 128 bf16)
#pragma unroll
  for (int p = 0; p < 4; ++p) {
    int r = p * 16 + rloc;
    int gr = row0 + r;
    uintx4 v = {0u, 0u, 0u, 0u};
    if (gr < n) v = *(const uintx4*)(Eo + (size_t)gr * 128 + c8);
    *(uintx4*)(Es + r * LDX + c8) = v;
  }
  // Wo (64 x 256 fp32 -> bf16, LDS row stride 272)
  {
    const int c8b   = (tid & 31) * 8;   // 0..248
    const int rloc8 = tid >> 5;         // 0..7
#pragma unroll
    for (int p = 0; p < 8; ++p) {
      int r = p * 8 + rloc8;
      const float* Wr = Wo + (size_t)r * 256 + c8b;
      *(uintx4*)(Wos + r * 272 + c8b) = pack8(*(const fltx4*)Wr, *(const fltx4*)(Wr + 4));
    }
  }
  __syncthreads();

  // ---- phase 2 compute: out = [Eo, x_b] Wo^T + bo (K=256, HOUT=64) ----
  floatx4 acc2[2][2];
#pragma unroll
  for (int i = 0; i < 2; ++i)
#pragma unroll
    for (int j = 0; j < 2; ++j) acc2[i][j] = (floatx4){0.f, 0.f, 0.f, 0.f};

#pragma unroll
  for (int k = 0; k < 8; ++k) {
    const int ko = (k & 3) * 32 + quad * 8;
    const unsigned short* Bsrc = (k < 4) ? Es : Xs;
    short8 aW[2], bX[2];
#pragma unroll
    for (int j = 0; j < 2; ++j)
      aW[j] = *(const short8*)(Wos + (wn * 32 + j * 16 + l15) * 272 + k * 32 + quad * 8);
#pragma unroll
    for (int i = 0; i < 2; ++i)
      bX[i] = *(const short8*)(Bsrc + (wm * 32 + i * 16 + l15) * LDX + ko);
#pragma unroll
    for (int i = 0; i < 2; ++i)
#pragma unroll
      for (int j = 0; j < 2; ++j)
        acc2[i][j] = __builtin_amdgcn_mfma_f32_16x16x32_bf16(
            aW[j], bX[i], acc2[i][j], 0, 0, 0);
  }

#pragma unroll
  for (int i = 0; i < 2; ++i) {
    int r = row0 + wm * 32 + i * 16 + l15;
    if (r >= n) continue;
#pragma unroll
    for (int j = 0; j < 2; ++j) {
      int c0 = wn * 32 + j * 16 + quad * 4;
      fltx4 bb = *(const fltx4*)(bo + c0);
      fltx4 o = {acc2[i][j][0] + bb.x, acc2[i][j][1] + bb.y,
                 acc2[i][j][2] + bb.z, acc2[i][j][3] + bb.w};
      __builtin_nontemporal_store(o, (fltx4*)(out + (size_t)r * 64 + c0));
    }
  }
}

// ---------------------------------------------------------------------------
extern "C" void kernel_launch(void* const* d_in, const int* in_sizes, int n_in,
                              void* d_out, int out_size, void* d_ws, size_t ws_size,
                              hipStream_t stream)
{
  const float* x     = (const float*)d_in[0];
  const int*   row_a = (const int*)d_in[1];
  const int*   col_a = (const int*)d_in[2];
  const float* val_a = (const float*)d_in[3];
  const int*   row_b = (const int*)d_in[4];
  const int*   col_b = (const int*)d_in[5];
  const float* val_b = (const float*)d_in[6];
  const float* Wa0 = (const float*)d_in[7];  const float* ba0 = (const float*)d_in[8];
  const float* Wa1 = (const float*)d_in[9];  const float* ba1 = (const float*)d_in[10];
  const float* Wb0 = (const float*)d_in[11]; const float* bb0 = (const float*)d_in[12];
  const float* Wb1 = (const float*)d_in[13]; const float* bb1 = (const float*)d_in[14];
  const float* Wm  = (const float*)d_in[15]; const float* bm  = (const float*)d_in[16];
  const float* Wo  = (const float*)d_in[17]; const float* bo  = (const float*)d_in[18];
  float* out = (float*)d_out;

  const int n = in_sizes[0] / 128;   // 50000
  const int E = in_sizes[1];         // 800000

  char* ws = (char*)d_ws;
  size_t off = 0;
  auto alloc = [&](size_t bytes) {
    void* p = ws + off;
    off = (off + bytes + 255) & ~(size_t)255;
    return p;
  };
  const size_t slab = (size_t)n * 128 * sizeof(unsigned short);
  unsigned short* A  = (unsigned short*)alloc(slab);  // h (branch a)
  unsigned short* B  = (unsigned short*)alloc(slab);  // spmm_a temp / g2
  unsigned short* C  = (unsigned short*)alloc(slab);  // g0
  unsigned short* D  = (unsigned short*)alloc(slab);  // g1
  unsigned short* Eo = (unsigned short*)alloc(slab);  // x_a
  unsigned short* F  = (unsigned short*)alloc(slab);  // spmm_b temp

  dim3 blk(256);
  const int nb64 = (n + 63) / 64;    // 782
  const int nsp  = (n + 15) / 16;    // 3125

  // 1. L0 pair: A = relu(x Wa0^T + ba0), C = relu(x Wb0^T + bb0)   [x fp32]
  mfma_linear_pair_kernel<true><<<dim3(nb64, 2), blk, 0, stream>>>(
      LinJob{x, Wa0, ba0, A}, LinJob{x, Wb0, bb0, C}, n);

  // 2. S pair 1: B = spmm_a(A), F = spmm_b(C)
  spmm_pair_kernel<<<dim3(nsp, 2), blk, 0, stream>>>(
      SpmmJob{row_a, col_a, val_a, A, B},
      SpmmJob{row_b, col_b, val_b, C, F}, E, n);

  // 3. L1 pair: A = relu(B Wa1^T + ba1), D = relu(F Wb1^T + bb1)
  mfma_linear_pair_kernel<false><<<dim3(nb64, 2), blk, 0, stream>>>(
      LinJob{B, Wa1, ba1, A}, LinJob{F, Wb1, bb1, D}, n);

  // 4. S pair 2: Eo = spmm_a(A) (x_a), B = spmm_b(D) (g2)
  spmm_pair_kernel<<<dim3(nsp, 2), blk, 0, stream>>>(
      SpmmJob{row_a, col_a, val_a, A, Eo},
      SpmmJob{row_b, col_b, val_b, D, B}, E, n);

  // 5. fused: x_b = relu([C,D,B] Wm^T + bm); out = [Eo, x_b] Wo^T + bo
  lm_lo_fused_kernel<<<dim3(nb64, 1), blk, 0, stream>>>(
      C, D, B, Wm, bm, Eo, Wo, bo, out, n);
}

// Round 8
// 331.584 us; speedup vs baseline: 1.1208x; 1.1208x over previous
//
#include <hip/hip_runtime.h>

// ---------------------------------------------------------------------------
// DualGCN round 8: 6 dispatches.
//   0. rowptr pair : rpa/rpb via parallel binary search (separate dispatch —
//                    in-spmm search regressed r7: serial 20-step chain/block)
//   1. L0 pair  : A=relu(x Wa0^T+ba0), C=relu(x Wb0^T+bb0)  [W fp32->bf16 on the fly]
//   2. S pair 1 : B=spmm_a(A), F=spmm_b(C)
//   3. L1 pair  : A=relu(B Wa1^T+ba1), D=relu(F Wb1^T+bb1)
//   4. S pair 2 : Eo=spmm_a(A), B=spmm_b(D)
//   5. LmLo     : x_b=relu([C,D,B] Wm^T+bm); out=[Eo,x_b] Wo^T+bo  (fused)
// bf16 slabs, fp32 accumulation. N=50000, E=800000, H=128, OUT=64.
// ---------------------------------------------------------------------------

typedef short short8 __attribute__((ext_vector_type(8)));
typedef float floatx4 __attribute__((ext_vector_type(4)));
typedef float floatx2 __attribute__((ext_vector_type(2)));
typedef int   intx4   __attribute__((ext_vector_type(4)));
typedef float fltx4   __attribute__((ext_vector_type(4)));
typedef unsigned uintx4 __attribute__((ext_vector_type(4)));

__device__ inline unsigned short f2bf(float f) {
  unsigned u = __builtin_bit_cast(unsigned, f);
  u += 0x7fffu + ((u >> 16) & 1u);      // round-to-nearest-even
  return (unsigned short)(u >> 16);
}
__device__ inline unsigned pack2(float a, float b) {
  return (unsigned)f2bf(a) | ((unsigned)f2bf(b) << 16);
}
__device__ inline float bf_lo(unsigned w) {
  return __builtin_bit_cast(float, w << 16);
}
__device__ inline float bf_hi(unsigned w) {
  return __builtin_bit_cast(float, w & 0xffff0000u);
}
__device__ inline uintx4 pack8(const fltx4& a, const fltx4& b) {
  uintx4 v;
  v.x = pack2(a.x, a.y); v.y = pack2(a.z, a.w);
  v.z = pack2(b.x, b.y); v.w = pack2(b.z, b.w);
  return v;
}

// ---------------------------------------------------------------------------
struct RpJob { const int* row; int* rowptr; };

// rowptr[i] = first edge index e with row[e] >= i  (row is sorted)
__global__ __launch_bounds__(256) void build_rowptr_pair_kernel(
    RpJob j0, RpJob j1, int E, int n)
{
  const RpJob J = blockIdx.y ? j1 : j0;
  int i = blockIdx.x * 256 + threadIdx.x;
  if (i > n) return;
  int lo = 0, hi = E;
  while (lo < hi) {
    int mid = (lo + hi) >> 1;
    if (J.row[mid] < i) lo = mid + 1; else hi = mid;
  }
  J.rowptr[i] = lo;
}

// ---------------------------------------------------------------------------
struct SpmmJob {
  const int* rp; const int* col; const float* val;
  const unsigned short* X; unsigned short* Y;
};

// Y[r,:] = sum_e val[e] * X[col[e],:]  (bf16 in, fp32 accum via pk_fma,
// bf16 out). 16 lanes/row, lane owns 8 bf16 (16 B). Edge loop unrolled x8 ->
// 8 independent 16 B gathers in flight per row-group. (round-6 proven body)
__global__ __launch_bounds__(256) void spmm_pair_kernel(
    SpmmJob j0, SpmmJob j1, int n)
{
  const SpmmJob J = blockIdx.y ? j1 : j0;
  const int g = blockIdx.x * 16 + (threadIdx.x >> 4);
  const int lane = threadIdx.x & 15;
  if (g >= n) return;
  const int e0 = J.rp[g], e1 = J.rp[g + 1];
  const size_t loff = (size_t)lane * 8;
  const unsigned short* __restrict__ X = J.X;
  const int* __restrict__ colp = J.col;
  const float* __restrict__ valp = J.val;

  floatx2 ac0 = {0.f, 0.f}, ac1 = {0.f, 0.f};
  floatx2 ac2 = {0.f, 0.f}, ac3 = {0.f, 0.f};

  auto accw = [&](float v, const uintx4& w) {
    floatx2 vv = {v, v};
    floatx2 x0 = {bf_lo(w.x), bf_hi(w.x)};
    floatx2 x1 = {bf_lo(w.y), bf_hi(w.y)};
    floatx2 x2 = {bf_lo(w.z), bf_hi(w.z)};
    floatx2 x3 = {bf_lo(w.w), bf_hi(w.w)};
    ac0 = __builtin_elementwise_fma(vv, x0, ac0);
    ac1 = __builtin_elementwise_fma(vv, x1, ac1);
    ac2 = __builtin_elementwise_fma(vv, x2, ac2);
    ac3 = __builtin_elementwise_fma(vv, x3, ac3);
  };
  auto acc1 = [&](int e) {
    uintx4 w = *(const uintx4*)(X + (size_t)colp[e] * 128 + loff);
    accw(valp[e], w);
  };

  int e = e0;
  int epro = (e0 + 7) & ~7;           // align to 8 for vector col/val loads
  if (epro > e1) epro = e1;
  for (; e < epro; ++e) acc1(e);
  for (; e + 8 <= e1; e += 8) {
    intx4 ca = __builtin_nontemporal_load((const intx4*)(colp + e));
    intx4 cb = __builtin_nontemporal_load((const intx4*)(colp + e + 4));
    fltx4 va = __builtin_nontemporal_load((const fltx4*)(valp + e));
    fltx4 vb = __builtin_nontemporal_load((const fltx4*)(valp + e + 4));
    uintx4 w0 = *(const uintx4*)(X + (size_t)ca.x * 128 + loff);
    uintx4 w1 = *(const uintx4*)(X + (size_t)ca.y * 128 + loff);
    uintx4 w2 = *(const uintx4*)(X + (size_t)ca.z * 128 + loff);
    uintx4 w3 = *(const uintx4*)(X + (size_t)ca.w * 128 + loff);
    uintx4 w4 = *(const uintx4*)(X + (size_t)cb.x * 128 + loff);
    uintx4 w5 = *(const uintx4*)(X + (size_t)cb.y * 128 + loff);
    uintx4 w6 = *(const uintx4*)(X + (size_t)cb.z * 128 + loff);
    uintx4 w7 = *(const uintx4*)(X + (size_t)cb.w * 128 + loff);
    accw(va.x, w0); accw(va.y, w1); accw(va.z, w2); accw(va.w, w3);
    accw(vb.x, w4); accw(vb.y, w5); accw(vb.z, w6); accw(vb.w, w7);
  }
  for (; e < e1; ++e) acc1(e);

  uintx4 o;
  o.x = pack2(ac0[0], ac0[1]); o.y = pack2(ac1[0], ac1[1]);
  o.z = pack2(ac2[0], ac2[1]); o.w = pack2(ac3[0], ac3[1]);
  __builtin_nontemporal_store(o, (uintx4*)(J.Y + (size_t)g * 128 + loff));
}

// ---------------------------------------------------------------------------
struct LinJob {
  const void* X;             // [n,128] bf16 slab (or fp32 if XFP32)
  const float* W;            // [128,128] fp32 row-major
  const float* b;            // [128] fp32
  unsigned short* Y;         // [n,128] bf16
};

// Paired LDS-tiled MFMA GEMM: Y = relu(X @ W.T + b). K=128, HOUT=128, BM=64.
// W staged fp32->bf16 on the fly. 4 waves in 2x2; operand swap (a=W, b=X) so
// each lane's 4 acc regs are 4 consecutive output cols. blockIdx.y = job.
template <bool XFP32>
__global__ __launch_bounds__(256, 3) void mfma_linear_pair_kernel(
    LinJob j0, LinJob j1, int n)
{
  constexpr int LDX = 136;
  __shared__ unsigned short Xs[64 * LDX];   // 17408 B
  __shared__ unsigned short Ws[128 * LDX];  // 34816 B

  const LinJob J = blockIdx.y ? j1 : j0;
  const int tid  = threadIdx.x;
  const int lane = tid & 63;
  const int wave = tid >> 6;
  const int wm   = wave >> 1;     // row half (32 rows)
  const int wn   = wave & 1;      // col half (64 cols)
  const int l15  = lane & 15;
  const int quad = lane >> 4;
  const int row0 = blockIdx.x * 64;

  const int c8   = (tid & 15) * 8;
  const int rloc = tid >> 4;

  // stage X tile: 64 rows x 128 bf16
#pragma unroll
  for (int p = 0; p < 4; ++p) {
    int r = p * 16 + rloc;
    int gr = row0 + r;
    uintx4 v = {0u, 0u, 0u, 0u};
    if (gr < n) {
      if (XFP32) {
        const float* Xr = (const float*)J.X + (size_t)gr * 128 + c8;
        v = pack8(*(const fltx4*)Xr, *(const fltx4*)(Xr + 4));
      } else {
        v = *(const uintx4*)((const unsigned short*)J.X + (size_t)gr * 128 + c8);
      }
    }
    *(uintx4*)(Xs + r * LDX + c8) = v;
  }
  // stage W tile: 128 x 128, fp32 -> bf16
#pragma unroll
  for (int p = 0; p < 8; ++p) {
    int r = p * 16 + rloc;
    const float* Wr = J.W + (size_t)r * 128 + c8;
    *(uintx4*)(Ws + r * LDX + c8) = pack8(*(const fltx4*)Wr, *(const fltx4*)(Wr + 4));
  }
  __syncthreads();

  floatx4 acc[2][4];
#pragma unroll
  for (int i = 0; i < 2; ++i)
#pragma unroll
    for (int j = 0; j < 4; ++j) acc[i][j] = (floatx4){0.f, 0.f, 0.f, 0.f};

#pragma unroll
  for (int k0 = 0; k0 < 128; k0 += 32) {
    const int ko = k0 + quad * 8;
    short8 aW[4], bX[2];
#pragma unroll
    for (int j = 0; j < 4; ++j)
      aW[j] = *(const short8*)(Ws + (wn * 64 + j * 16 + l15) * LDX + ko);
#pragma unroll
    for (int i = 0; i < 2; ++i)
      bX[i] = *(const short8*)(Xs + (wm * 32 + i * 16 + l15) * LDX + ko);
#pragma unroll
    for (int i = 0; i < 2; ++i)
#pragma unroll
      for (int j = 0; j < 4; ++j)
        acc[i][j] = __builtin_amdgcn_mfma_f32_16x16x32_bf16(
            aW[j], bX[i], acc[i][j], 0, 0, 0);
  }

#pragma unroll
  for (int i = 0; i < 2; ++i) {
    int r = row0 + wm * 32 + i * 16 + l15;
    if (r >= n) continue;
#pragma unroll
    for (int j = 0; j < 4; ++j) {
      int c0 = wn * 64 + j * 16 + quad * 4;
      fltx4 bb = *(const fltx4*)(J.b + c0);
      float v0 = fmaxf(acc[i][j][0] + bb.x, 0.f);
      float v1 = fmaxf(acc[i][j][1] + bb.y, 0.f);
      float v2 = fmaxf(acc[i][j][2] + bb.z, 0.f);
      float v3 = fmaxf(acc[i][j][3] + bb.w, 0.f);
      uint2 o; o.x = pack2(v0, v1); o.y = pack2(v2, v3);
      *(uint2*)(J.Y + (size_t)r * 128 + c0) = o;
    }
  }
}

// ---------------------------------------------------------------------------
// Fused merge: x_b = relu([C,D,B] @ Wm.T + bm); out = [Eo, x_b] @ Wo.T + bo.
// Phase 1: K=384 in 3 slab chunks (Wm fp32 staged per chunk), acc -> x_b.
// Phase 2: x_b -> LDS (bf16), Eo tile + full Wo staged, K=256 MFMA, fp32 out.
__global__ __launch_bounds__(256, 2) void lm_lo_fused_kernel(
    const unsigned short* __restrict__ Cs, const unsigned short* __restrict__ Ds,
    const unsigned short* __restrict__ Bs,
    const float* __restrict__ Wm, const float* __restrict__ bm,
    const unsigned short* __restrict__ Eo,
    const float* __restrict__ Wo, const float* __restrict__ bo,
    float* __restrict__ out, int n)
{
  constexpr int LDX = 136;
  __shared__ unsigned short Xs[64 * LDX];   // phase1: X chunk; phase2: x_b
  __shared__ unsigned short U[26112];       // phase1: Ws[128*136]; phase2: Es[64*136] + Wos[64*272]
  unsigned short* Ws  = U;
  unsigned short* Es  = U;
  unsigned short* Wos = U + 64 * LDX;

  const int tid  = threadIdx.x;
  const int lane = tid & 63;
  const int wave = tid >> 6;
  const int wm   = wave >> 1;
  const int wn   = wave & 1;
  const int l15  = lane & 15;
  const int quad = lane >> 4;
  const int row0 = blockIdx.x * 64;

  const int c8   = (tid & 15) * 8;
  const int rloc = tid >> 4;

  // ---- phase 1: x_b accumulation (K=384) ----
  floatx4 acc[2][4];
#pragma unroll
  for (int i = 0; i < 2; ++i)
#pragma unroll
    for (int j = 0; j < 4; ++j) acc[i][j] = (floatx4){0.f, 0.f, 0.f, 0.f};

  for (int kc = 0; kc < 3; ++kc) {
    const unsigned short* Xp = (kc == 0) ? Cs : (kc == 1) ? Ds : Bs;
#pragma unroll
    for (int p = 0; p < 4; ++p) {
      int r = p * 16 + rloc;
      int gr = row0 + r;
      uintx4 v = {0u, 0u, 0u, 0u};
      if (gr < n) v = *(const uintx4*)(Xp + (size_t)gr * 128 + c8);
      *(uintx4*)(Xs + r * LDX + c8) = v;
    }
#pragma unroll
    for (int p = 0; p < 8; ++p) {
      int r = p * 16 + rloc;
      const float* Wr = Wm + (size_t)r * 384 + kc * 128 + c8;
      *(uintx4*)(Ws + r * LDX + c8) = pack8(*(const fltx4*)Wr, *(const fltx4*)(Wr + 4));
    }
    __syncthreads();
#pragma unroll
    for (int k0 = 0; k0 < 128; k0 += 32) {
      const int ko = k0 + quad * 8;
      short8 aW[4], bX[2];
#pragma unroll
      for (int j = 0; j < 4; ++j)
        aW[j] = *(const short8*)(Ws + (wn * 64 + j * 16 + l15) * LDX + ko);
#pragma unroll
      for (int i = 0; i < 2; ++i)
        bX[i] = *(const short8*)(Xs + (wm * 32 + i * 16 + l15) * LDX + ko);
#pragma unroll
      for (int i = 0; i < 2; ++i)
#pragma unroll
        for (int j = 0; j < 4; ++j)
          acc[i][j] = __builtin_amdgcn_mfma_f32_16x16x32_bf16(
              aW[j], bX[i], acc[i][j], 0, 0, 0);
    }
    __syncthreads();
  }

  // ---- phase 2 staging: x_b->Xs, Eo->Es, Wo->Wos ----
#pragma unroll
  for (int i = 0; i < 2; ++i) {
    int r = wm * 32 + i * 16 + l15;
#pragma unroll
    for (int j = 0; j < 4; ++j) {
      int c0 = wn * 64 + j * 16 + quad * 4;
      fltx4 bb = *(const fltx4*)(bm + c0);
      float v0 = fmaxf(acc[i][j][0] + bb.x, 0.f);
      float v1 = fmaxf(acc[i][j][1] + bb.y, 0.f);
      float v2 = fmaxf(acc[i][j][2] + bb.z, 0.f);
      float v3 = fmaxf(acc[i][j][3] + bb.w, 0.f);
      *(unsigned*)(Xs + r * LDX + c0)     = pack2(v0, v1);
      *(unsigned*)(Xs + r * LDX + c0 + 2) = pack2(v2, v3);
    }
  }
  // Eo tile (64 x 128 bf16)
#pragma unroll
  for (int p = 0; p < 4; ++p) {
    int r = p * 16 + rloc;
    int gr = row0 + r;
    uintx4 v = {0u, 0u, 0u, 0u};
    if (gr < n) v = *(const uintx4*)(Eo + (size_t)gr * 128 + c8);
    *(uintx4*)(Es + r * LDX + c8) = v;
  }
  // Wo (64 x 256 fp32 -> bf16, LDS row stride 272)
  {
    const int c8b   = (tid & 31) * 8;   // 0..248
    const int rloc8 = tid >> 5;         // 0..7
#pragma unroll
    for (int p = 0; p < 8; ++p) {
      int r = p * 8 + rloc8;
      const float* Wr = Wo + (size_t)r * 256 + c8b;
      *(uintx4*)(Wos + r * 272 + c8b) = pack8(*(const fltx4*)Wr, *(const fltx4*)(Wr + 4));
    }
  }
  __syncthreads();

  // ---- phase 2 compute: out = [Eo, x_b] Wo^T + bo (K=256, HOUT=64) ----
  floatx4 acc2[2][2];
#pragma unroll
  for (int i = 0; i < 2; ++i)
#pragma unroll
    for (int j = 0; j < 2; ++j) acc2[i][j] = (floatx4){0.f, 0.f, 0.f, 0.f};

#pragma unroll
  for (int k = 0; k < 8; ++k) {
    const int ko = (k & 3) * 32 + quad * 8;
    const unsigned short* Bsrc = (k < 4) ? Es : Xs;
    short8 aW[2], bX[2];
#pragma unroll
    for (int j = 0; j < 2; ++j)
      aW[j] = *(const short8*)(Wos + (wn * 32 + j * 16 + l15) * 272 + k * 32 + quad * 8);
#pragma unroll
    for (int i = 0; i < 2; ++i)
      bX[i] = *(const short8*)(Bsrc + (wm * 32 + i * 16 + l15) * LDX + ko);
#pragma unroll
    for (int i = 0; i < 2; ++i)
#pragma unroll
      for (int j = 0; j < 2; ++j)
        acc2[i][j] = __builtin_amdgcn_mfma_f32_16x16x32_bf16(
            aW[j], bX[i], acc2[i][j], 0, 0, 0);
  }

#pragma unroll
  for (int i = 0; i < 2; ++i) {
    int r = row0 + wm * 32 + i * 16 + l15;
    if (r >= n) continue;
#pragma unroll
    for (int j = 0; j < 2; ++j) {
      int c0 = wn * 32 + j * 16 + quad * 4;
      fltx4 bb = *(const fltx4*)(bo + c0);
      fltx4 o = {acc2[i][j][0] + bb.x, acc2[i][j][1] + bb.y,
                 acc2[i][j][2] + bb.z, acc2[i][j][3] + bb.w};
      __builtin_nontemporal_store(o, (fltx4*)(out + (size_t)r * 64 + c0));
    }
  }
}

// ---------------------------------------------------------------------------
extern "C" void kernel_launch(void* const* d_in, const int* in_sizes, int n_in,
                              void* d_out, int out_size, void* d_ws, size_t ws_size,
                              hipStream_t stream)
{
  const float* x     = (const float*)d_in[0];
  const int*   row_a = (const int*)d_in[1];
  const int*   col_a = (const int*)d_in[2];
  const float* val_a = (const float*)d_in[3];
  const int*   row_b = (const int*)d_in[4];
  const int*   col_b = (const int*)d_in[5];
  const float* val_b = (const float*)d_in[6];
  const float* Wa0 = (const float*)d_in[7];  const float* ba0 = (const float*)d_in[8];
  const float* Wa1 = (const float*)d_in[9];  const float* ba1 = (const float*)d_in[10];
  const float* Wb0 = (const float*)d_in[11]; const float* bb0 = (const float*)d_in[12];
  const float* Wb1 = (const float*)d_in[13]; const float* bb1 = (const float*)d_in[14];
  const float* Wm  = (const float*)d_in[15]; const float* bm  = (const float*)d_in[16];
  const float* Wo  = (const float*)d_in[17]; const float* bo  = (const float*)d_in[18];
  float* out = (float*)d_out;

  const int n = in_sizes[0] / 128;   // 50000
  const int E = in_sizes[1];         // 800000

  char* ws = (char*)d_ws;
  size_t off = 0;
  auto alloc = [&](size_t bytes) {
    void* p = ws + off;
    off = (off + bytes + 255) & ~(size_t)255;
    return p;
  };
  int* rpa = (int*)alloc((size_t)(n + 1) * sizeof(int));
  int* rpb = (int*)alloc((size_t)(n + 1) * sizeof(int));
  const size_t slab = (size_t)n * 128 * sizeof(unsigned short);
  unsigned short* A  = (unsigned short*)alloc(slab);  // h (branch a)
  unsigned short* B  = (unsigned short*)alloc(slab);  // spmm_a temp / g2
  unsigned short* C  = (unsigned short*)alloc(slab);  // g0
  unsigned short* D  = (unsigned short*)alloc(slab);  // g1
  unsigned short* Eo = (unsigned short*)alloc(slab);  // x_a
  unsigned short* F  = (unsigned short*)alloc(slab);  // spmm_b temp

  dim3 blk(256);
  const int nb64 = (n + 63) / 64;    // 782
  const int nsp  = (n + 15) / 16;    // 3125

  // 0. rowptrs (paired, parallel binary search)
  build_rowptr_pair_kernel<<<dim3((n + 1 + 255) / 256, 2), blk, 0, stream>>>(
      RpJob{row_a, rpa}, RpJob{row_b, rpb}, E, n);

  // 1. L0 pair: A = relu(x Wa0^T + ba0), C = relu(x Wb0^T + bb0)   [x fp32]
  mfma_linear_pair_kernel<true><<<dim3(nb64, 2), blk, 0, stream>>>(
      LinJob{x, Wa0, ba0, A}, LinJob{x, Wb0, bb0, C}, n);

  // 2. S pair 1: B = spmm_a(A), F = spmm_b(C)
  spmm_pair_kernel<<<dim3(nsp, 2), blk, 0, stream>>>(
      SpmmJob{rpa, col_a, val_a, A, B},
      SpmmJob{rpb, col_b, val_b, C, F}, n);

  // 3. L1 pair: A = relu(B Wa1^T + ba1), D = relu(F Wb1^T + bb1)
  mfma_linear_pair_kernel<false><<<dim3(nb64, 2), blk, 0, stream>>>(
      LinJob{B, Wa1, ba1, A}, LinJob{F, Wb1, bb1, D}, n);

  // 4. S pair 2: Eo = spmm_a(A) (x_a), B = spmm_b(D) (g2)
  spmm_pair_kernel<<<dim3(nsp, 2), blk, 0, stream>>>(
      SpmmJob{rpa, col_a, val_a, A, Eo},
      SpmmJob{rpb, col_b, val_b, D, B}, n);

  // 5. fused: x_b = relu([C,D,B] Wm^T + bm); out = [Eo, x_b] Wo^T + bo
  lm_lo_fused_kernel<<<dim3(nb64, 1), blk, 0, stream>>>(
      C, D, B, Wm, bm, Eo, Wo, bo, out, n);
}